// Round 4
// baseline (1486.438 us; speedup 1.0000x reference)
//
#include <hip/hip_runtime.h>
#include <math.h>

// ModelParallelCrossEntropy: loss = mean_b [ log(sum_v exp(x[b,v])) - x[b,label[b]] ]
// Single fused streaming dispatch. Each row split into 25 chunks (one block each,
// 20 floats/thread in registers). Last-arriving block per row merges the row's
// partials; last row-finisher computes the batch mean. Device-scope atomics for
// cross-XCD visibility; all reduction orders fixed -> deterministic.

#define VOCAB 128000
#define BATCH 1024
#define SPLITS 25
#define TPB 256
#define CHUNK (VOCAB / SPLITS)        // 5120 floats per block
#define NEG_SENT -1.0e30f

typedef float f32x4 __attribute__((ext_vector_type(4)));

__global__ __launch_bounds__(TPB) void ce_fused_kernel(const float* __restrict__ logits,
                                                       const int* __restrict__ labels,
                                                       float* __restrict__ part_m,
                                                       float* __restrict__ part_s,
                                                       float* __restrict__ row_loss,
                                                       float* __restrict__ row_xl,
                                                       int* __restrict__ row_count,
                                                       int* __restrict__ done_rows,
                                                       float* __restrict__ out) {
    const int blk = blockIdx.x;
    const int row = blk / SPLITS;
    const int split = blk % SPLITS;
    const float* rowp = logits + (size_t)row * VOCAB;
    const f32x4* __restrict__ rp =
        reinterpret_cast<const f32x4*>(rowp + split * CHUNK);

    // ---- streaming phase: 5 independent float4 nontemporal loads per thread ----
    const int t = threadIdx.x;
    f32x4 v0 = __builtin_nontemporal_load(rp + t);
    f32x4 v1 = __builtin_nontemporal_load(rp + t + TPB);
    f32x4 v2 = __builtin_nontemporal_load(rp + t + 2 * TPB);
    f32x4 v3 = __builtin_nontemporal_load(rp + t + 3 * TPB);
    f32x4 v4 = __builtin_nontemporal_load(rp + t + 4 * TPB);

    float m0 = fmaxf(fmaxf(v0[0], v0[1]), fmaxf(v0[2], v0[3]));
    float m1 = fmaxf(fmaxf(v1[0], v1[1]), fmaxf(v1[2], v1[3]));
    float m2 = fmaxf(fmaxf(v2[0], v2[1]), fmaxf(v2[2], v2[3]));
    float m3 = fmaxf(fmaxf(v3[0], v3[1]), fmaxf(v3[2], v3[3]));
    float m4 = fmaxf(fmaxf(v4[0], v4[1]), fmaxf(v4[2], v4[3]));
    float m = fmaxf(fmaxf(fmaxf(m0, m1), fmaxf(m2, m3)), m4);

    float s0 = __expf(v0[0] - m) + __expf(v0[1] - m) + __expf(v0[2] - m) + __expf(v0[3] - m);
    float s1 = __expf(v1[0] - m) + __expf(v1[1] - m) + __expf(v1[2] - m) + __expf(v1[3] - m);
    float s2 = __expf(v2[0] - m) + __expf(v2[1] - m) + __expf(v2[2] - m) + __expf(v2[3] - m);
    float s3 = __expf(v3[0] - m) + __expf(v3[1] - m) + __expf(v3[2] - m) + __expf(v3[3] - m);
    float s4 = __expf(v4[0] - m) + __expf(v4[1] - m) + __expf(v4[2] - m) + __expf(v4[3] - m);
    float s = ((s0 + s1) + (s2 + s3)) + s4;

    // ---- 64-lane butterfly reduction of (m, s) ----
    #pragma unroll
    for (int off = 1; off < 64; off <<= 1) {
        float mo = __shfl_xor(m, off);
        float so = __shfl_xor(s, off);
        float mn = fmaxf(m, mo);
        s = s * __expf(m - mn) + so * __expf(mo - mn);
        m = mn;
    }

    __shared__ float sm[TPB / 64], ss[TPB / 64];
    const int wave = threadIdx.x >> 6;
    const int lane = threadIdx.x & 63;
    if (lane == 0) { sm[wave] = m; ss[wave] = s; }
    __syncthreads();

    // ---- thread 0: block merge, publish partials, bump row counter ----
    int old = 0;
    if (threadIdx.x == 0) {
        float M = sm[0], S = ss[0];
        #pragma unroll
        for (int w = 1; w < TPB / 64; ++w) {
            float mn = fmaxf(M, sm[w]);
            S = S * __expf(M - mn) + ss[w] * __expf(sm[w] - mn);
            M = mn;
        }
        __hip_atomic_store(&part_m[blk], M, __ATOMIC_RELAXED, __HIP_MEMORY_SCOPE_AGENT);
        __hip_atomic_store(&part_s[blk], S, __ATOMIC_RELAXED, __HIP_MEMORY_SCOPE_AGENT);

        // exactly one chunk per row owns the label
        int lab = labels[row];
        int lo = split * CHUNK;
        if (lab >= lo && lab < lo + CHUNK)
            __hip_atomic_store(&row_xl[row], rowp[lab], __ATOMIC_RELAXED, __HIP_MEMORY_SCOPE_AGENT);

        old = __hip_atomic_fetch_add(&row_count[row], 1, __ATOMIC_ACQ_REL, __HIP_MEMORY_SCOPE_AGENT);
    }

    // ---- wave 0: last block of the row merges the row's partials ----
    if (threadIdx.x < 64) {
        old = __shfl(old, 0);
        if (old == SPLITS - 1) {
            float M = NEG_SENT, S = 0.0f;
            if (lane < SPLITS) {
                M = __hip_atomic_load(&part_m[row * SPLITS + lane], __ATOMIC_RELAXED, __HIP_MEMORY_SCOPE_AGENT);
                S = __hip_atomic_load(&part_s[row * SPLITS + lane], __ATOMIC_RELAXED, __HIP_MEMORY_SCOPE_AGENT);
            }
            #pragma unroll
            for (int off = 1; off < 64; off <<= 1) {
                float mo = __shfl_xor(M, off);
                float so = __shfl_xor(S, off);
                float mn = fmaxf(M, mo);
                S = S * __expf(M - mn) + so * __expf(mo - mn);
                M = mn;
            }
            int old2 = 0;
            if (lane == 0) {
                float xl = __hip_atomic_load(&row_xl[row], __ATOMIC_RELAXED, __HIP_MEMORY_SCOPE_AGENT);
                float loss = (M - xl) + __logf(S);
                __hip_atomic_store(&row_loss[row], loss, __ATOMIC_RELAXED, __HIP_MEMORY_SCOPE_AGENT);
                old2 = __hip_atomic_fetch_add(done_rows, 1, __ATOMIC_ACQ_REL, __HIP_MEMORY_SCOPE_AGENT);
            }
            old2 = __shfl(old2, 0);

            // ---- very last row-finisher: batch mean ----
            if (old2 == BATCH - 1) {
                float acc = 0.0f;
                #pragma unroll
                for (int j = 0; j < BATCH / 64; ++j)
                    acc += __hip_atomic_load(&row_loss[j * 64 + lane], __ATOMIC_RELAXED, __HIP_MEMORY_SCOPE_AGENT);
                #pragma unroll
                for (int off = 1; off < 64; off <<= 1)
                    acc += __shfl_xor(acc, off);
                if (lane == 0) out[0] = acc / (float)BATCH;
            }
        }
    }
}

extern "C" void kernel_launch(void* const* d_in, const int* in_sizes, int n_in,
                              void* d_out, int out_size, void* d_ws, size_t ws_size,
                              hipStream_t stream) {
    const float* logits = (const float*)d_in[0];
    const int* labels = (const int*)d_in[1];

    float* part_m = (float*)d_ws;                     // 25600 floats
    float* part_s = part_m + BATCH * SPLITS;          // 25600 floats
    float* row_loss = part_s + BATCH * SPLITS;        // 1024 floats
    float* row_xl = row_loss + BATCH;                 // 1024 floats
    int* row_count = (int*)(row_xl + BATCH);          // 1024 ints
    int* done_rows = row_count + BATCH;               // 1 int
    float* out = (float*)d_out;

    // zero the completion counters (graph-capture-safe async memset)
    hipMemsetAsync(row_count, 0, (BATCH + 1) * sizeof(int), stream);

    ce_fused_kernel<<<BATCH * SPLITS, TPB, 0, stream>>>(logits, labels,
                                                        part_m, part_s, row_loss,
                                                        row_xl, row_count, done_rows,
                                                        out);
}

// Round 5
// 86.639 us; speedup vs baseline: 17.1567x; 17.1567x over previous
//
#include <hip/hip_runtime.h>
#include <math.h>

// ModelParallelCrossEntropy: loss = mean_b [ log(sum_v exp(x[b,v])) - x[b,label[b]] ]
// One streaming pass; each row split into 25 chunks, each thread owns exactly
// 20 floats (5x float4 nontemporal loads) -> max + exp-sum entirely in registers.
// Partials stored TRANSPOSED [split][row] so the combine kernel reads coalesced.
// NOTE (R3 lesson): do NOT fuse via agent-scope acq_rel atomics — each one emits
// L2 writeback/invalidate on gfx950 and collapses streaming BW 37x.

#define VOCAB 128000
#define BATCH 1024
#define SPLITS 25
#define TPB 256
#define CHUNK (VOCAB / SPLITS)        // 5120 floats per block

typedef float f32x4 __attribute__((ext_vector_type(4)));

__global__ __launch_bounds__(TPB) void ce_partial_kernel(const float* __restrict__ logits,
                                                         const int* __restrict__ labels,
                                                         float* __restrict__ part_m,   // [SPLITS][BATCH]
                                                         float* __restrict__ part_s,   // [SPLITS][BATCH]
                                                         float* __restrict__ row_xl) {
    const int blk = blockIdx.x;
    const int row = blk / SPLITS;
    const int split = blk % SPLITS;
    const float* rowp = logits + (size_t)row * VOCAB;
    const f32x4* __restrict__ rp =
        reinterpret_cast<const f32x4*>(rowp + split * CHUNK);

    // ---- streaming phase: 5 independent float4 nontemporal loads per thread ----
    const int t = threadIdx.x;
    f32x4 v0 = __builtin_nontemporal_load(rp + t);
    f32x4 v1 = __builtin_nontemporal_load(rp + t + TPB);
    f32x4 v2 = __builtin_nontemporal_load(rp + t + 2 * TPB);
    f32x4 v3 = __builtin_nontemporal_load(rp + t + 3 * TPB);
    f32x4 v4 = __builtin_nontemporal_load(rp + t + 4 * TPB);

    float m0 = fmaxf(fmaxf(v0[0], v0[1]), fmaxf(v0[2], v0[3]));
    float m1 = fmaxf(fmaxf(v1[0], v1[1]), fmaxf(v1[2], v1[3]));
    float m2 = fmaxf(fmaxf(v2[0], v2[1]), fmaxf(v2[2], v2[3]));
    float m3 = fmaxf(fmaxf(v3[0], v3[1]), fmaxf(v3[2], v3[3]));
    float m4 = fmaxf(fmaxf(v4[0], v4[1]), fmaxf(v4[2], v4[3]));
    float m = fmaxf(fmaxf(fmaxf(m0, m1), fmaxf(m2, m3)), m4);

    float s0 = __expf(v0[0] - m) + __expf(v0[1] - m) + __expf(v0[2] - m) + __expf(v0[3] - m);
    float s1 = __expf(v1[0] - m) + __expf(v1[1] - m) + __expf(v1[2] - m) + __expf(v1[3] - m);
    float s2 = __expf(v2[0] - m) + __expf(v2[1] - m) + __expf(v2[2] - m) + __expf(v2[3] - m);
    float s3 = __expf(v3[0] - m) + __expf(v3[1] - m) + __expf(v3[2] - m) + __expf(v3[3] - m);
    float s4 = __expf(v4[0] - m) + __expf(v4[1] - m) + __expf(v4[2] - m) + __expf(v4[3] - m);
    float s = ((s0 + s1) + (s2 + s3)) + s4;

    // ---- 64-lane butterfly reduction of (m, s) ----
    #pragma unroll
    for (int off = 1; off < 64; off <<= 1) {
        float mo = __shfl_xor(m, off);
        float so = __shfl_xor(s, off);
        float mn = fmaxf(m, mo);
        s = s * __expf(m - mn) + so * __expf(mo - mn);
        m = mn;
    }

    __shared__ float sm[TPB / 64], ss[TPB / 64];
    const int wave = threadIdx.x >> 6;
    if ((threadIdx.x & 63) == 0) { sm[wave] = m; ss[wave] = s; }
    __syncthreads();

    if (threadIdx.x == 0) {
        float M = sm[0], S = ss[0];
        #pragma unroll
        for (int w = 1; w < TPB / 64; ++w) {
            float mn = fmaxf(M, sm[w]);
            S = S * __expf(M - mn) + ss[w] * __expf(sm[w] - mn);
            M = mn;
        }
        part_m[split * BATCH + row] = M;     // transposed: coalesced in combine
        part_s[split * BATCH + row] = S;

        // exactly one chunk per row owns the label
        int lab = labels[row];
        int lo = split * CHUNK;
        if (lab >= lo && lab < lo + CHUNK) row_xl[row] = rowp[lab];
    }
}

#define CTPB 1024
__global__ __launch_bounds__(CTPB) void ce_combine_kernel(const float* __restrict__ part_m,
                                                          const float* __restrict__ part_s,
                                                          const float* __restrict__ row_xl,
                                                          float* __restrict__ out) {
    const int r = threadIdx.x;           // one row per thread; coalesced reads
    float M = part_m[r];
    float S = part_s[r];
    #pragma unroll
    for (int k = 1; k < SPLITS; ++k) {
        float pm = part_m[k * BATCH + r];
        float ps = part_s[k * BATCH + r];
        float mn = fmaxf(M, pm);
        S = S * __expf(M - mn) + ps * __expf(pm - mn);
        M = mn;
    }
    float loss = (M - row_xl[r]) + __logf(S);

    #pragma unroll
    for (int off = 1; off < 64; off <<= 1) loss += __shfl_xor(loss, off);

    __shared__ float sv[CTPB / 64];
    if ((threadIdx.x & 63) == 0) sv[threadIdx.x >> 6] = loss;
    __syncthreads();
    if (threadIdx.x == 0) {
        float tacc = 0.0f;
        #pragma unroll
        for (int w = 0; w < CTPB / 64; ++w) tacc += sv[w];
        out[0] = tacc / (float)BATCH;
    }
}

extern "C" void kernel_launch(void* const* d_in, const int* in_sizes, int n_in,
                              void* d_out, int out_size, void* d_ws, size_t ws_size,
                              hipStream_t stream) {
    const float* logits = (const float*)d_in[0];
    const int* labels = (const int*)d_in[1];
    float* part_m = (float*)d_ws;                            // 25600 floats
    float* part_s = part_m + BATCH * SPLITS;                 // 25600 floats
    float* row_xl = part_s + BATCH * SPLITS;                 // 1024 floats
    float* out = (float*)d_out;

    ce_partial_kernel<<<BATCH * SPLITS, TPB, 0, stream>>>(logits, labels,
                                                          part_m, part_s, row_xl);
    ce_combine_kernel<<<1, CTPB, 0, stream>>>(part_m, part_s, row_xl, out);
}